// Round 6
// baseline (174.269 us; speedup 1.0000x reference)
//
#include <hip/hip_runtime.h>
#include <math.h>

#define DD 32
#define MM 16
#define TROWH 80   // half elems per tbl row: t[32] | it[32] | cj[8] | pad[8]  (160B)

typedef _Float16 half8  __attribute__((ext_vector_type(8)));
typedef _Float16 half2t __attribute__((ext_vector_type(2)));
typedef int      vi4    __attribute__((ext_vector_type(4)));

__device__ __forceinline__ void load8f4(const float* __restrict__ p, float* r) {
    const float4* q = (const float4*)p;
#pragma unroll
    for (int i = 0; i < 8; ++i) {
        float4 v = q[i];
        r[4*i+0] = v.x; r[4*i+1] = v.y; r[4*i+2] = v.z; r[4*i+3] = v.w;
    }
}

// Fused prep: [0, NU*4) threads convert user_table to fp16 (8 elems each);
// [NU*4, NU*4 + NI*4) threads build the fp16 item tbl (4 threads per item).
// One dispatch so both halves run concurrently under the harness's 256MB
// workspace-fill window instead of serializing after each other (round-5 bug:
// convert->precompute serial chain = 53us, starved by the fill).
__global__ void prep(const float* __restrict__ user_table,
                     const float* __restrict__ item_table,
                     const float* __restrict__ W_bil,
                     const float* __restrict__ W1,
                     _Float16* __restrict__ ut_h,
                     _Float16* __restrict__ tbl,
                     int NU, int NI) {
    int g = blockIdx.x * blockDim.x + threadIdx.x;
    int nconv = NU * 4;                  // NU*DD/8 threads, 8 elems each
    if (g < nconv) {
        const float4* p = (const float4*)user_table + 2 * (size_t)g;
        float4 a = p[0], b = p[1];
        half8 h;
        h[0] = (_Float16)a.x; h[1] = (_Float16)a.y; h[2] = (_Float16)a.z; h[3] = (_Float16)a.w;
        h[4] = (_Float16)b.x; h[5] = (_Float16)b.y; h[6] = (_Float16)b.z; h[7] = (_Float16)b.w;
        *((half8*)ut_h + g) = h;
        return;
    }
    int gi = g - nconv;
    int i = gi >> 2, q = gi & 3;
    if (i >= NI) return;
    int ko = q * 8;
    const float* row = item_table + (size_t)i * DD;
    float it[DD];
    load8f4(row, it);                    // same addr across the quad -> broadcast
    _Float16* o = tbl + (size_t)i * TROWH;

    half8 th;
#pragma unroll
    for (int k = 0; k < 8; ++k) {
        const float* w = W_bil + (ko + k) * DD;
        float s0 = 0.f, s1 = 0.f, s2 = 0.f, s3 = 0.f;
#pragma unroll
        for (int e = 0; e < DD; e += 4) {
            s0 = fmaf(w[e+0], it[e+0], s0);
            s1 = fmaf(w[e+1], it[e+1], s1);
            s2 = fmaf(w[e+2], it[e+2], s2);
            s3 = fmaf(w[e+3], it[e+3], s3);
        }
        th[k] = (_Float16)((s0 + s1) + (s2 + s3));
    }
    *(half8*)(o + ko) = th;

    {   // it-slice copy via named vectors (L1-hot re-load; rule #20 safe)
        const float4* ip = (const float4*)(row + ko);
        float4 a = ip[0], c = ip[1];
        half8 ih;
        ih[0] = (_Float16)a.x; ih[1] = (_Float16)a.y; ih[2] = (_Float16)a.z; ih[3] = (_Float16)a.w;
        ih[4] = (_Float16)c.x; ih[5] = (_Float16)c.y; ih[6] = (_Float16)c.z; ih[7] = (_Float16)c.w;
        *(half8*)(o + DD + ko) = ih;
    }

    int j0 = 2 * q;
    float c0 = 0.f, c1 = 0.f;
#pragma unroll
    for (int e = 0; e < DD; ++e) {
        c0 = fmaf(W1[j0 * 96 + 64 + e], it[e], c0);
        c1 = fmaf(W1[(j0 + 1) * 96 + 64 + e], it[e], c1);
    }
    half2t ch; ch[0] = (_Float16)c0; ch[1] = (_Float16)c1;
    *(half2t*)(o + 64 + 2 * q) = ch;
}

__device__ __forceinline__ float dot8f(const float* a, const float* b) {
    float s0 = fmaf(a[0], b[0], fmaf(a[1], b[1], 0.f));
    float s1 = fmaf(a[2], b[2], fmaf(a[3], b[3], 0.f));
    float s2 = fmaf(a[4], b[4], fmaf(a[5], b[5], 0.f));
    float s3 = fmaf(a[6], b[6], fmaf(a[7], b[7], 0.f));
    return (s0 + s1) + (s2 + s3);
}

// Quad-cooperative main, full-MLP member phase:
//  - all 16 slot ids clamped (inactive -> ids[0]: same line as slot 0, L1 hit)
//  - all 16 half8 row-slice gathers issued up front (one latency for the phase)
//  - consume in batches of 4: 4 dots, then 8 INDEPENDENT shfl_xor back-to-back
//    (pipelined, vs 2 serial shfls per member), len-gated scores, fin fmas.
// No exec-mask divergence anywhere in the member phase.
__global__ __launch_bounds__(256)
void bilinear_main_h(const int* __restrict__ item_inputs,
                     const int* __restrict__ member_ids,
                     const unsigned char* __restrict__ member_mask,
                     const _Float16* __restrict__ ut_h,
                     const _Float16* __restrict__ tbl,
                     const float* __restrict__ b_bil,
                     const float* __restrict__ W1,
                     const float* __restrict__ b1v,
                     const float* __restrict__ W2,
                     const float* __restrict__ b2v,
                     float* __restrict__ out, int Btot) {
    int tid = blockIdx.x * blockDim.x + threadIdx.x;
    int b = tid >> 2;
    if (b >= Btot) return;
    int q = tid & 3;
    int ko = q * 8;

    int item = __builtin_nontemporal_load(item_inputs + b);
    const uint4 mv = *(const uint4*)(member_mask + (size_t)b * MM);
    int len = __popc(mv.x & 0x01010101u) + __popc(mv.y & 0x01010101u) +
              __popc(mv.z & 0x01010101u) + __popc(mv.w & 0x01010101u);

    // All 16 ids (every lane needs every member's id for its dim-slice gather).
    const vi4* mp = (const vi4*)(member_ids + (size_t)b * MM);
    vi4 w0 = __builtin_nontemporal_load(mp + 0);
    vi4 w1 = __builtin_nontemporal_load(mp + 1);
    vi4 w2 = __builtin_nontemporal_load(mp + 2);
    vi4 w3 = __builtin_nontemporal_load(mp + 3);
    int idc[MM];
    idc[0] = w0[0];
    idc[1]  = (1  < len) ? w0[1] : w0[0];
    idc[2]  = (2  < len) ? w0[2] : w0[0];
    idc[3]  = (3  < len) ? w0[3] : w0[0];
    idc[4]  = (4  < len) ? w1[0] : w0[0];
    idc[5]  = (5  < len) ? w1[1] : w0[0];
    idc[6]  = (6  < len) ? w1[2] : w0[0];
    idc[7]  = (7  < len) ? w1[3] : w0[0];
    idc[8]  = (8  < len) ? w2[0] : w0[0];
    idc[9]  = (9  < len) ? w2[1] : w0[0];
    idc[10] = (10 < len) ? w2[2] : w0[0];
    idc[11] = (11 < len) ? w2[3] : w0[0];
    idc[12] = (12 < len) ? w3[0] : w0[0];
    idc[13] = (13 < len) ? w3[1] : w0[0];
    idc[14] = (14 < len) ? w3[2] : w0[0];
    idc[15] = (15 < len) ? w3[3] : w0[0];

    // Issue ALL 16 gathers (64 VGPRs in flight -> one memory latency total).
    half8 r[MM];
#pragma unroll
    for (int k = 0; k < MM; ++k)
        r[k] = *(const half8*)(ut_h + (size_t)idc[k] * DD + ko);

    // t slice (independent load, overlaps the gathers).
    const _Float16* tb = tbl + (size_t)item * TROWH;
    half8 th = *(const half8*)(tb + ko);
    float t[8];
#pragma unroll
    for (int k = 0; k < 8; ++k) t[k] = (float)th[k];

    float bb = b_bil[0];
    float fin[8];
#pragma unroll
    for (int k = 0; k < 8; ++k) fin[k] = 0.f;

#pragma unroll
    for (int bi = 0; bi < 4; ++bi) {
        float m0[8], m1[8], m2[8], m3[8];
#pragma unroll
        for (int k = 0; k < 8; ++k) {
            m0[k] = (float)r[4*bi+0][k];
            m1[k] = (float)r[4*bi+1][k];
            m2[k] = (float)r[4*bi+2][k];
            m3[k] = (float)r[4*bi+3][k];
        }
        float s0 = dot8f(m0, t);
        float s1 = dot8f(m1, t);
        float s2 = dot8f(m2, t);
        float s3 = dot8f(m3, t);
        // batched butterflies (independent -> pipelined)
        s0 += __shfl_xor(s0, 1); s1 += __shfl_xor(s1, 1);
        s2 += __shfl_xor(s2, 1); s3 += __shfl_xor(s3, 1);
        s0 += __shfl_xor(s0, 2); s1 += __shfl_xor(s1, 2);
        s2 += __shfl_xor(s2, 2); s3 += __shfl_xor(s3, 2);
        s0 = (4*bi+0 < len) ? s0 + bb : 0.f;
        s1 = (4*bi+1 < len) ? s1 + bb : 0.f;
        s2 = (4*bi+2 < len) ? s2 + bb : 0.f;
        s3 = (4*bi+3 < len) ? s3 + bb : 0.f;
#pragma unroll
        for (int k = 0; k < 8; ++k) {
            float f = fmaf(s0, m0[k], fmaf(s1, m1[k], fin[k]));
            fin[k] = fmaf(s2, m2[k], fmaf(s3, m3[k], f));
        }
    }

    // it slice (same tbl row, already cached).
    half8 ih = *(const half8*)(tb + DD + ko);
    float it8[8];
#pragma unroll
    for (int k = 0; k < 8; ++k) it8[k] = (float)ih[k];
    float p8[8];
#pragma unroll
    for (int k = 0; k < 8; ++k) p8[k] = fin[k] * it8[k];

    float u[8];
#pragma unroll
    for (int j = 0; j < 8; ++j) {
        const float* wr = W1 + j * 96 + ko;
        float4 wa0 = *(const float4*)(wr);
        float4 wa1 = *(const float4*)(wr + 4);
        float4 wb0 = *(const float4*)(wr + 32);
        float4 wb1 = *(const float4*)(wr + 36);
        float x = 0.f, y = 0.f;
        x = fmaf(wa0.x, p8[0], x); y = fmaf(wb0.x, fin[0], y);
        x = fmaf(wa0.y, p8[1], x); y = fmaf(wb0.y, fin[1], y);
        x = fmaf(wa0.z, p8[2], x); y = fmaf(wb0.z, fin[2], y);
        x = fmaf(wa0.w, p8[3], x); y = fmaf(wb0.w, fin[3], y);
        x = fmaf(wa1.x, p8[4], x); y = fmaf(wb1.x, fin[4], y);
        x = fmaf(wa1.y, p8[5], x); y = fmaf(wb1.y, fin[5], y);
        x = fmaf(wa1.z, p8[6], x); y = fmaf(wb1.z, fin[6], y);
        x = fmaf(wa1.w, p8[7], x); y = fmaf(wb1.w, fin[7], y);
        u[j] = x + y;
    }
#pragma unroll
    for (int j = 0; j < 8; ++j) {
        u[j] += __shfl_xor(u[j], 1);
        u[j] += __shfl_xor(u[j], 2);
    }

    if (q == 0) {
        half8 ch = *(const half8*)(tb + 64);
        float z = b2v[0];
#pragma unroll
        for (int j = 0; j < 8; ++j) {
            float hv = u[j] + (float)ch[j] + b1v[j];
            hv = hv > 0.f ? hv : 0.f;
            z = fmaf(W2[j], hv, z);
        }
        __builtin_nontemporal_store(1.f / (1.f + __expf(-z)), out + b);
    }
}

// fp32 fallback (no workspace): round-4 quad kernel, tables computed inline.
__global__ __launch_bounds__(256)
void bilinear_main_f(const int* __restrict__ item_inputs,
                     const int* __restrict__ member_ids,
                     const unsigned char* __restrict__ member_mask,
                     const float* __restrict__ user_table,
                     const float* __restrict__ item_table,
                     const float* __restrict__ W_bil,
                     const float* __restrict__ b_bil,
                     const float* __restrict__ W1,
                     const float* __restrict__ b1v,
                     const float* __restrict__ W2,
                     const float* __restrict__ b2v,
                     float* __restrict__ out, int Btot) {
    int tid = blockIdx.x * blockDim.x + threadIdx.x;
    int b = tid >> 2;
    if (b >= Btot) return;
    int q = tid & 3;
    int ko = q * 8;

    int item = item_inputs[b];
    const uint4 mv = *(const uint4*)(member_mask + (size_t)b * MM);
    int len = __popc(mv.x & 0x01010101u) + __popc(mv.y & 0x01010101u) +
              __popc(mv.z & 0x01010101u) + __popc(mv.w & 0x01010101u);

    float itf[DD];
    load8f4(item_table + (size_t)item * DD, itf);
    float t[8];
#pragma unroll
    for (int k = 0; k < 8; ++k) {
        const float* w = W_bil + (ko + k) * DD;
        float s0 = 0.f, s1 = 0.f, s2 = 0.f, s3 = 0.f;
#pragma unroll
        for (int e = 0; e < DD; e += 4) {
            s0 = fmaf(w[e+0], itf[e+0], s0);
            s1 = fmaf(w[e+1], itf[e+1], s1);
            s2 = fmaf(w[e+2], itf[e+2], s2);
            s3 = fmaf(w[e+3], itf[e+3], s3);
        }
        t[k] = (s0 + s1) + (s2 + s3);
    }

    float bb = b_bil[0];
    float fin[8];
#pragma unroll
    for (int k = 0; k < 8; ++k) fin[k] = 0.f;

    const int* idp = member_ids + (size_t)b * MM;
    for (int m = 0; m < len; ++m) {
        int id = idp[m];
        const float4* up = (const float4*)(user_table + (size_t)id * DD + ko);
        float4 a = up[0], c = up[1];
        float me[8] = {a.x, a.y, a.z, a.w, c.x, c.y, c.z, c.w};
        float s = dot8f(me, t);
        s += __shfl_xor(s, 1); s += __shfl_xor(s, 2);
        s += bb;
#pragma unroll
        for (int k = 0; k < 8; ++k) fin[k] = fmaf(s, me[k], fin[k]);
    }

    const float4* ip = (const float4*)(item_table + (size_t)item * DD + ko);
    float4 ia = ip[0], ic = ip[1];
    float it8[8] = {ia.x, ia.y, ia.z, ia.w, ic.x, ic.y, ic.z, ic.w};
    float p8[8];
#pragma unroll
    for (int k = 0; k < 8; ++k) p8[k] = fin[k] * it8[k];

    float u[8];
#pragma unroll
    for (int j = 0; j < 8; ++j) {
        const float* wr = W1 + j * 96 + ko;
        float4 wa0 = *(const float4*)(wr);
        float4 wa1 = *(const float4*)(wr + 4);
        float4 wb0 = *(const float4*)(wr + 32);
        float4 wb1 = *(const float4*)(wr + 36);
        float x = 0.f, y = 0.f;
        x = fmaf(wa0.x, p8[0], x); y = fmaf(wb0.x, fin[0], y);
        x = fmaf(wa0.y, p8[1], x); y = fmaf(wb0.y, fin[1], y);
        x = fmaf(wa0.z, p8[2], x); y = fmaf(wb0.z, fin[2], y);
        x = fmaf(wa0.w, p8[3], x); y = fmaf(wb0.w, fin[3], y);
        x = fmaf(wa1.x, p8[4], x); y = fmaf(wb1.x, fin[4], y);
        x = fmaf(wa1.y, p8[5], x); y = fmaf(wb1.y, fin[5], y);
        x = fmaf(wa1.z, p8[6], x); y = fmaf(wb1.z, fin[6], y);
        x = fmaf(wa1.w, p8[7], x); y = fmaf(wb1.w, fin[7], y);
        u[j] = x + y;
    }
#pragma unroll
    for (int j = 0; j < 8; ++j) {
        u[j] += __shfl_xor(u[j], 1);
        u[j] += __shfl_xor(u[j], 2);
    }

    if (q == 0) {
        float z = b2v[0];
#pragma unroll
        for (int j = 0; j < 8; ++j) {
            float cj = 0.f;
#pragma unroll
            for (int d = 0; d < DD; ++d) cj = fmaf(W1[j * 96 + 64 + d], itf[d], cj);
            float hv = u[j] + cj + b1v[j];
            hv = hv > 0.f ? hv : 0.f;
            z = fmaf(W2[j], hv, z);
        }
        __builtin_nontemporal_store(1.f / (1.f + __expf(-z)), out + b);
    }
}

extern "C" void kernel_launch(void* const* d_in, const int* in_sizes, int n_in,
                              void* d_out, int out_size, void* d_ws, size_t ws_size,
                              hipStream_t stream) {
    const int*           item_inputs = (const int*)d_in[0];
    const int*           member_ids  = (const int*)d_in[1];
    const unsigned char* member_mask = (const unsigned char*)d_in[2];
    const float*         user_table  = (const float*)d_in[3];
    const float*         item_table  = (const float*)d_in[4];
    const float*         W_bil       = (const float*)d_in[5];
    const float*         b_bil       = (const float*)d_in[6];
    const float*         W1          = (const float*)d_in[7];
    const float*         b1          = (const float*)d_in[8];
    const float*         W2          = (const float*)d_in[9];
    const float*         b2          = (const float*)d_in[10];
    float* out = (float*)d_out;

    int Btot = in_sizes[0];
    int NU   = in_sizes[3] / DD;
    int NI   = in_sizes[4] / DD;

    size_t tbl_bytes = (size_t)NI * TROWH * sizeof(_Float16);
    size_t ut_off    = (tbl_bytes + 255) & ~(size_t)255;
    size_t need      = ut_off + (size_t)NU * DD * sizeof(_Float16);

    int blk = 256;
    long long nthreads = (long long)Btot * 4;
    if (ws_size >= need) {
        _Float16* tbl  = (_Float16*)d_ws;
        _Float16* ut_h = (_Float16*)((char*)d_ws + ut_off);
        int nprep = NU * 4 + NI * 4;
        prep<<<(nprep + blk - 1) / blk, blk, 0, stream>>>(
            user_table, item_table, W_bil, W1, ut_h, tbl, NU, NI);
        bilinear_main_h<<<(int)((nthreads + blk - 1) / blk), blk, 0, stream>>>(
            item_inputs, member_ids, member_mask, ut_h, tbl,
            b_bil, W1, b1, W2, b2, out, Btot);
    } else {
        bilinear_main_f<<<(int)((nthreads + blk - 1) / blk), blk, 0, stream>>>(
            item_inputs, member_ids, member_mask, user_table, item_table,
            W_bil, b_bil, W1, b1, W2, b2, out, Btot);
    }
}